// Round 9
// baseline (101.992 us; speedup 1.0000x reference)
//
#include <hip/hip_runtime.h>
#include <hip/hip_bf16.h>

// Sizes (fixed by the problem)
#define E_CNT 131072
#define NP_CNT 65536
#define D_P 80
#define D_C 48
#define D_ADD 16
#define K1 1152   // 144*8
#define K2 512    // 64*8
#define MAXDEG 32

typedef _Float16 f16x8 __attribute__((ext_vector_type(8)));
typedef _Float16 f16x2 __attribute__((ext_vector_type(2)));
typedef float f32x4 __attribute__((ext_vector_type(4)));

union F16x8U { f16x2 h2[4]; f16x8 v8; };

__device__ __forceinline__ float silu_f(float x){
  return x / (1.0f + __expf(-x));
}
__device__ __forceinline__ f16x2 pkrtz(float a, float b){
  return __builtin_bit_cast(f16x2, __builtin_amdgcn_cvt_pkrtz(a, b));
}

// ---------------------------------------------------------------------------
// W in FRAGMENT-LINEAR order: wtf[ks][h][kk], kk = k - ks*32 (32 f16 = 64 B).
// Logical k = ks*32 + q*8 + j (q=kk>>3, j=kk&7); f = q*NKS + ks; g = j.
// A wave's B-frag read at step ks = 1 KB CONTIGUOUS global load (L2-hot,
// identical across all blocks) -> no LDS staging, no barriers in the K-loop.
// ---------------------------------------------------------------------------
__global__ void prep_w_kernel(const float* __restrict__ W1, const float* __restrict__ W2,
                              _Float16* __restrict__ wtf1, _Float16* __restrict__ wtf2){
  int id = blockIdx.x * 256 + threadIdx.x;
  if (id < 64 * K1){
    int ks = id >> 11, rem = id & 2047, h = rem >> 5, kk = rem & 31;
    int q = kk >> 3, j = kk & 7;
    wtf1[id] = (_Float16)W1[(q * 36 + ks) * 512 + j * 64 + h];
  } else {
    int id2 = id - 64 * K1;
    int ks = id2 >> 11, rem = id2 & 2047, h = rem >> 5, kk = rem & 31;
    int q = kk >> 3, j = kk & 7;
    wtf2[id2] = (_Float16)W2[(q * 16 + ks) * 512 + j * 64 + h];
  }
}

// ---------------------------------------------------------------------------
// CSR build: zero, slot-fill, 3-step scan -> off[] and perm[] (edges by dst)
// ---------------------------------------------------------------------------
__global__ void zero_cnt_kernel(int* __restrict__ cnt, int* __restrict__ bsum){
  const int gid = blockIdx.x * 256 + threadIdx.x;
  if (gid < NP_CNT) cnt[gid] = 0;
  else bsum[gid - NP_CNT] = 0;
}
__global__ void fill_slots_kernel(const int* __restrict__ eidx,
                                  int* __restrict__ cnt, int* __restrict__ slots){
  const int e = blockIdx.x * 256 + threadIdx.x;
  const int d = eidx[E_CNT + e];
  const int p = atomicAdd(&cnt[d], 1);
  if (p < MAXDEG) slots[d * MAXDEG + p] = e;
}
__global__ void scanA_kernel(const int* __restrict__ cnt, int* __restrict__ bsum){
  const int t = threadIdx.x;
  int v = min(cnt[blockIdx.x * 256 + t], MAXDEG);
  #pragma unroll
  for (int o = 32; o; o >>= 1) v += __shfl_down(v, o);
  __shared__ int s[4];
  if ((t & 63) == 0) s[t >> 6] = v;
  __syncthreads();
  if (t == 0) bsum[blockIdx.x] = s[0] + s[1] + s[2] + s[3];
}
__global__ void scanB_kernel(const int* __restrict__ bsum, int* __restrict__ boff){
  __shared__ int s[256];
  const int t = threadIdx.x;
  const int v = bsum[t];
  s[t] = v; __syncthreads();
  for (int o = 1; o < 256; o <<= 1){
    int x = (t >= o) ? s[t - o] : 0;
    __syncthreads();
    s[t] += x;
    __syncthreads();
  }
  boff[t] = s[t] - v;
}
__global__ void scanC_emit_kernel(const int* __restrict__ cnt, const int* __restrict__ slots,
                                  const int* __restrict__ boff,
                                  int* __restrict__ off, int* __restrict__ perm){
  __shared__ int s[256];
  const int t = threadIdx.x;
  const int n = blockIdx.x * 256 + t;
  const int v = min(cnt[n], MAXDEG);
  s[t] = v; __syncthreads();
  for (int o = 1; o < 256; o <<= 1){
    int x = (t >= o) ? s[t - o] : 0;
    __syncthreads();
    s[t] += x;
    __syncthreads();
  }
  const int o0 = boff[blockIdx.x] + s[t] - v;
  off[n] = o0;
  for (int j = 0; j < v; ++j) perm[o0 + j] = slots[n * MAXDEG + j];
}

// ---------------------------------------------------------------------------
// Fused 2-layer GEMM over permuted edges. Barrier-free K-loops:
//  - B-frags read directly from fragment-linear W in global (L2-resident,
//    1 KB coalesced per wave per step).
//  - A-frags built in registers: x gathered per-lane (perm -> x_p streams),
//    depth-3 register prefetch, fully unrolled (static indices).
//  - m1 crosses layers through LDS [256][72] f16 (only barrier in kernel).
//  - m2 written coalesced in PERM order.
// ---------------------------------------------------------------------------
__global__ __launch_bounds__(512, 4) void fused_gemm_kernel(
    const float* __restrict__ x_p, const float* __restrict__ x_c,
    const int* __restrict__ eidx, const float* __restrict__ ea,
    const float* __restrict__ addf, const int* __restrict__ perm,
    const _Float16* __restrict__ wtf1, const float* __restrict__ b1,
    const _Float16* __restrict__ wtf2, const float* __restrict__ b2,
    _Float16* __restrict__ m2p)
{
  __shared__ _Float16 s_m1[256 * 72];       // 36.9 KB (only LDS)

  const int t    = threadIdx.x;
  const int lane = t & 63;
  const int wv   = t >> 6;
  const int wm   = wv >> 1;             // 0..3 edge quarter
  const int wn   = wv & 1;              // 0..1 h half
  const int l15  = lane & 15;
  const int q    = lane >> 4;           // 0..3

  const int EB = blockIdx.x * 256;      // position base (perm space)

  // B-frag f16 index base: wtf[ks][h][kk] -> ks*2048 + h*32 + kk
  const int wb = (wn * 32 + l15) * 32 + q * 8;

  // per-mt edge data (perm'd)
  f16x2 apk[4][4];
  int offP[4], offC[4], offA[4];
  #pragma unroll
  for (int mt = 0; mt < 4; ++mt){
    const int e = perm[EB + wm * 64 + mt * 16 + l15] & (E_CNT - 1);
    const float4* ap = reinterpret_cast<const float4*>(ea + (size_t)e * 8);
    float4 a0 = ap[0], a1 = ap[1];
    apk[mt][0] = pkrtz(a0.x, a0.y);
    apk[mt][1] = pkrtz(a0.z, a0.w);
    apk[mt][2] = pkrtz(a1.x, a1.y);
    apk[mt][3] = pkrtz(a1.z, a1.w);
    const int dn = eidx[E_CNT + e];
    const int sn = eidx[e];
    offP[mt] = dn * D_P;
    offC[mt] = sn * D_C - D_P;
    offA[mt] = e * D_ADD - (D_P + D_C);
  }

  f32x4 acc[4][2];
  #pragma unroll
  for (int mt = 0; mt < 4; ++mt){
    acc[mt][0] = f32x4{0.f,0.f,0.f,0.f};
    acc[mt][1] = f32x4{0.f,0.f,0.f,0.f};
  }

  float4 xb[3][4];                      // depth-3 rotating x prefetch
  auto FETCHX = [&](int c, float4* dst){
    const int o = q * 36 + 4 * c;
    #pragma unroll
    for (int mt = 0; mt < 4; ++mt){
      const float* p = (o < D_P) ? (x_p + offP[mt] + o)
                     : (o < D_P + D_C) ? (x_c + offC[mt] + o)
                     : (addf + offA[mt] + o);
      dst[mt] = *reinterpret_cast<const float4*>(p);
    }
  };

  // ================= LAYER 1 (9 chunks of K=128, no barriers) ============
  FETCHX(0, xb[0]); FETCHX(1, xb[1]); FETCHX(2, xb[2]);
  #pragma unroll
  for (int c = 0; c < 9; ++c){
    float4 cur[4];
    #pragma unroll
    for (int mt = 0; mt < 4; ++mt) cur[mt] = xb[c % 3][mt];
    if (c + 3 < 9) FETCHX(c + 3, xb[c % 3]);
    #pragma unroll
    for (int ksl = 0; ksl < 4; ++ksl){
      const int ks = c * 4 + ksl;
      f16x8 Bf[2];
      #pragma unroll
      for (int nt = 0; nt < 2; ++nt)
        Bf[nt] = __builtin_bit_cast(f16x8,
            *reinterpret_cast<const uint4*>(wtf1 + ks * 2048 + nt * 512 + wb));
      #pragma unroll
      for (int mt = 0; mt < 4; ++mt){
        const float xv = (ksl == 0) ? cur[mt].x : (ksl == 1) ? cur[mt].y
                       : (ksl == 2) ? cur[mt].z : cur[mt].w;
        f16x2 xh = pkrtz(xv, xv);
        F16x8U A;
        #pragma unroll
        for (int j = 0; j < 4; ++j) A.h2[j] = xh * apk[mt][j];
        acc[mt][0] = __builtin_amdgcn_mfma_f32_16x16x32_f16(A.v8, Bf[0], acc[mt][0], 0, 0, 0);
        acc[mt][1] = __builtin_amdgcn_mfma_f32_16x16x32_f16(A.v8, Bf[1], acc[mt][1], 0, 0, 0);
      }
    }
  }

  // ---- epilogue 1: +b1, SiLU -> s_m1 (f16). C/D: col=l15, row=q*4+r
  {
    float bv[2];
    bv[0] = b1[wn * 32 + l15];
    bv[1] = b1[wn * 32 + 16 + l15];
    #pragma unroll
    for (int mt = 0; mt < 4; ++mt){
      #pragma unroll
      for (int nt = 0; nt < 2; ++nt){
        #pragma unroll
        for (int r = 0; r < 4; ++r){
          float s = silu_f(acc[mt][nt][r] + bv[nt]);
          const int eo = wm * 64 + mt * 16 + q * 4 + r;
          const int h  = wn * 32 + nt * 16 + l15;
          s_m1[eo * 72 + h] = (_Float16)s;
        }
      }
    }
  }
  __syncthreads();   // the ONLY barrier

  // ---- preload layer-2 A-data from LDS m1
  uint4 md[4][2];
  #pragma unroll
  for (int mt = 0; mt < 4; ++mt){
    const int eo = wm * 64 + mt * 16 + l15;
    const uint4* mp = reinterpret_cast<const uint4*>(&s_m1[eo * 72 + q * 16]);
    md[mt][0] = mp[0];
    md[mt][1] = mp[1];
    acc[mt][0] = f32x4{0.f,0.f,0.f,0.f};
    acc[mt][1] = f32x4{0.f,0.f,0.f,0.f};
  }

  // ================= LAYER 2 (16 k-steps, no barriers) ===================
  #pragma unroll
  for (int ks = 0; ks < 16; ++ks){
    f16x8 Bf[2];
    #pragma unroll
    for (int nt = 0; nt < 2; ++nt)
      Bf[nt] = __builtin_bit_cast(f16x8,
          *reinterpret_cast<const uint4*>(wtf2 + ks * 2048 + nt * 512 + wb));
    #pragma unroll
    for (int mt = 0; mt < 4; ++mt){
      const unsigned comp = (ks < 8)
          ? ((ks >> 1) == 0 ? md[mt][0].x : (ks >> 1) == 1 ? md[mt][0].y
           : (ks >> 1) == 2 ? md[mt][0].z : md[mt][0].w)
          : (((ks - 8) >> 1) == 0 ? md[mt][1].x : ((ks - 8) >> 1) == 1 ? md[mt][1].y
           : ((ks - 8) >> 1) == 2 ? md[mt][1].z : md[mt][1].w);
      const unsigned v = (ks & 1) ? (comp >> 16) : (comp & 0xffffu);
      f16x2 xh = __builtin_bit_cast(f16x2, v | (v << 16));
      F16x8U A;
      #pragma unroll
      for (int j = 0; j < 4; ++j) A.h2[j] = xh * apk[mt][j];
      acc[mt][0] = __builtin_amdgcn_mfma_f32_16x16x32_f16(A.v8, Bf[0], acc[mt][0], 0, 0, 0);
      acc[mt][1] = __builtin_amdgcn_mfma_f32_16x16x32_f16(A.v8, Bf[1], acc[mt][1], 0, 0, 0);
    }
  }

  // ---- epilogue 2: +b2, SiLU -> m2p (perm order, coalesced)
  {
    float bv[2];
    bv[0] = b2[wn * 32 + l15];
    bv[1] = b2[wn * 32 + 16 + l15];
    #pragma unroll
    for (int mt = 0; mt < 4; ++mt){
      #pragma unroll
      for (int nt = 0; nt < 2; ++nt){
        #pragma unroll
        for (int r = 0; r < 4; ++r){
          float s = silu_f(acc[mt][nt][r] + bv[nt]);
          const int eo = wm * 64 + mt * 16 + q * 4 + r;
          const int h  = wn * 32 + nt * 16 + l15;
          m2p[(size_t)(EB + eo) * 64 + h] = (_Float16)s;
        }
      }
    }
  }
}

// ---------------------------------------------------------------------------
// combine: out[n] = concat(x_p[n], sum_{j<d} m2p[off[n]+j])   (8 lanes/node)
// m2p rows for a node are CONTIGUOUS (perm order) -> streaming reads.
// ---------------------------------------------------------------------------
__global__ __launch_bounds__(256) void combine_kernel(
    const float* __restrict__ x_p, const int* __restrict__ cnt,
    const int* __restrict__ off, const _Float16* __restrict__ m2p,
    float* __restrict__ out)
{
  const int gid = blockIdx.x * 256 + threadIdx.x;
  const int n = gid >> 3;
  const int r = gid & 7;
  const float* ps = x_p + (size_t)n * D_P;
  float* po = out + (size_t)n * 144;
  #pragma unroll
  for (int i = 0; i < 3; ++i){
    const int j4 = r + 8 * i;
    if (j4 < 20)
      *reinterpret_cast<float4*>(po + 4 * j4) = *reinterpret_cast<const float4*>(ps + 4 * j4);
  }
  float s[8] = {0.f,0.f,0.f,0.f,0.f,0.f,0.f,0.f};
  const int o0 = off[n];
  const int d  = min(cnt[n], MAXDEG);
  for (int j = 0; j < d; ++j){
    const uint4 mv = *reinterpret_cast<const uint4*>(m2p + (size_t)(o0 + j) * 64 + r * 8);
    f16x8 mh = __builtin_bit_cast(f16x8, mv);
    #pragma unroll
    for (int k = 0; k < 8; ++k) s[k] += (float)mh[k];
  }
  float4 o0v = make_float4(s[0], s[1], s[2], s[3]);
  float4 o1v = make_float4(s[4], s[5], s[6], s[7]);
  *reinterpret_cast<float4*>(po + 80 + r * 8)     = o0v;
  *reinterpret_cast<float4*>(po + 80 + r * 8 + 4) = o1v;
}

extern "C" void kernel_launch(void* const* d_in, const int* in_sizes, int n_in,
                              void* d_out, int out_size, void* d_ws, size_t ws_size,
                              hipStream_t stream){
  const float* x_p  = (const float*)d_in[0];
  const float* x_c  = (const float*)d_in[1];
  const int*   eidx = (const int*)d_in[2];
  const float* ea   = (const float*)d_in[3];
  // d_in[4] = batch (unused)
  const float* addf = (const float*)d_in[5];
  const float* W1   = (const float*)d_in[6];
  const float* b1   = (const float*)d_in[7];
  const float* W2   = (const float*)d_in[8];
  const float* b2   = (const float*)d_in[9];
  float* out = (float*)d_out;

  char* ws = (char*)d_ws;
  _Float16* wtf1 = (_Float16*)(ws);                // 147456 B
  _Float16* wtf2 = (_Float16*)(ws + 163840);       //  65536 B
  int* cnt   = (int*)(ws + 262144);                // 256 KB
  int* bsum  = (int*)(ws + 524288);                // 1 KB
  int* boff  = (int*)(ws + 525312);                // 1 KB
  int* off   = (int*)(ws + 526336);                // 256 KB
  int* slots = (int*)(ws + 788480);                // 8 MB
  int* perm  = (int*)(ws + 9177088);               // 512 KB
  _Float16* m2p = (_Float16*)(ws + 9701376);       // 16.78 MB

  prep_w_kernel<<<(64 * K1 + 64 * K2) / 256, 256, 0, stream>>>(W1, W2, wtf1, wtf2);
  zero_cnt_kernel<<<(NP_CNT + 256) / 256, 256, 0, stream>>>(cnt, bsum);
  fill_slots_kernel<<<E_CNT / 256, 256, 0, stream>>>(eidx, cnt, slots);
  scanA_kernel<<<NP_CNT / 256, 256, 0, stream>>>(cnt, bsum);
  scanB_kernel<<<1, 256, 0, stream>>>(bsum, boff);
  scanC_emit_kernel<<<NP_CNT / 256, 256, 0, stream>>>(cnt, slots, boff, off, perm);
  fused_gemm_kernel<<<E_CNT / 256, 512, 0, stream>>>(
      x_p, x_c, eidx, ea, addf, perm, wtf1, b1, wtf2, b2, m2p);
  combine_kernel<<<NP_CNT * 8 / 256, 256, 0, stream>>>(x_p, cnt, off, m2p, out);
}